// Round 3
// baseline (1903.669 us; speedup 1.0000x reference)
//
#include <hip/hip_runtime.h>
#include <math.h>

#define BB 128
#define T2 2050
#define TT 2049
#define HH 64
#define GG 448   // 7*H
#define KK 100
#define NE 103   // K+3
#define TCHUNK 128
#define NCHUNK 17   // ceil(2049/128)

#define LOG2E 1.44269504088896340736f
#define LN2   0.69314718055994530942f

typedef short bf16x8 __attribute__((ext_vector_type(8)));  // 8 bf16 bit-patterns (4 VGPRs)
typedef float f32x4  __attribute__((ext_vector_type(4)));

// ---- fast transcendentals (native v_exp_f32 / v_log_f32 / v_rcp_f32) ----
__device__ __forceinline__ float frcp(float x) { return __builtin_amdgcn_rcpf(x); }

__device__ __forceinline__ float sigmoid_fast(float x) {
    return frcp(1.f + exp2f(-x * LOG2E));
}
__device__ __forceinline__ float tanh_fast(float x) {
    float e = exp2f(x * (2.f * LOG2E));
    return 1.f - 2.f * frcp(1.f + e);
}
__device__ __forceinline__ float softplus_fast(float x) {
    float t = exp2f(-fabsf(x) * LOG2E);
    return fmaxf(x, 0.f) + LN2 * log2f(1.f + t);
}
__device__ __forceinline__ float expn_fast(float x) {   // e^x
    return exp2f(x * LOG2E);
}

// ---- bf16 split helpers (RNE) ----
__device__ __forceinline__ unsigned short bf16_rne(float f) {
    unsigned int u = __builtin_bit_cast(unsigned int, f);
    unsigned int r = u + 0x7FFFu + ((u >> 16) & 1u);
    return (unsigned short)(r >> 16);
}
__device__ __forceinline__ float bf16_to_f(unsigned short s) {
    unsigned int u = ((unsigned int)s) << 16;
    return __builtin_bit_cast(float, u);
}

// pre_emb[e][t] = sum_k in_emb[e][k] * Wx[k][t] + bias[t]   (103 x 448)
__global__ void pre_emb_kernel(const float* __restrict__ in_emb,
                               const float* __restrict__ Wx,
                               const float* __restrict__ bias,
                               float* __restrict__ pre_emb) {
    int e = blockIdx.x;
    int t = threadIdx.x;
    float acc = bias[t];
#pragma unroll
    for (int k = 0; k < HH; ++k)
        acc = fmaf(in_emb[e * HH + k], Wx[k * GG + t], acc);
    pre_emb[e * GG + t] = acc;
}

// One block per batch row; 4 waves, ONE barrier per step, MFMA gate GEMV.
//  - wave w owns elements e in [16w, 16w+16); it computes ALL 7 gates for
//    them: 7 N-groups of 16 cols (col = g*64 + 16w + (l&15)), K=64.
//  - Wh is register-resident as bf16 hi/lo B-fragments (split-bf16, 3 MFMA
//    products -> fp32-level accuracy). 42 mfma/wave/step, split into two
//    independent 3-deep accumulator chains per gate (latency, not thruput).
//  - A-frag rows and C-in rows are replicated, so EVERY lane's acc[0] holds
//    the true gate value for element 16w+(l&15): state update is lane-local,
//    no gate exchange through LDS at all.
//  - h is published as bf16 hi/lo into a double-buffered LDS region; per
//    step LDS = 16x ds_read_b128 + 8x ds_write_b16 per wave (vs the old
//    112 broadcast b128 + 49 b32 that saturated the LDS pipe at ~1640cy).
//  - h history (f32) goes to out[b,t,0:64] for the logits kernel.
__launch_bounds__(256, 1)
__global__ void scan_kernel(const int* __restrict__ event,
                            const float* __restrict__ dtime,
                            const float* __restrict__ pre_emb,
                            const float* __restrict__ Wh,
                            float* __restrict__ out) {
    const int b   = blockIdx.x;
    const int tid = threadIdx.x;
    const int w   = tid >> 6;     // wave 0..3
    const int l   = tid & 63;     // lane
    const int q   = l >> 4;       // quarter 0..3
    const int m   = l & 15;       // sub-lane 0..15
    const int e   = (w << 4) | m; // element this lane owns

    __shared__ __align__(16) unsigned short hs_hi[2][HH];
    __shared__ __align__(16) unsigned short hs_lo[2][HH];

    // ---- B fragments (Wh), hi/lo split, register-resident ----
    // B[k][n]: lane l holds B[32*kh + 8*q + j][m]; n-col = g*64 + 16w + m
    bf16x8 Bhi[7][2], Blo[7][2];
#pragma unroll
    for (int g = 0; g < 7; ++g) {
#pragma unroll
        for (int kh = 0; kh < 2; ++kh) {
            const int col = g * 64 + e;
            bf16x8 bh, bl;
#pragma unroll
            for (int j = 0; j < 8; ++j) {
                const int k = kh * 32 + q * 8 + j;
                const float v = Wh[k * GG + col];
                const unsigned short hi = bf16_rne(v);
                const float lof = v - bf16_to_f(hi);
                bh[j] = (short)hi;
                bl[j] = (short)bf16_rne(lof);
            }
            Bhi[g][kh] = bh;
            Blo[g][kh] = bl;
        }
    }

    if (tid < HH) { hs_hi[0][tid] = 0; hs_lo[0][tid] = 0; }

    const int*   ev_row  = event + b * T2;
    const float* dt_row  = dtime + b * T2;
    float*       out_row = out + (size_t)b * TT * KK;

    // pipelines: pre_cur[g] = pre-activation for THIS iter; evn = event for
    // next iter's pre; dt_cur = dt for this iter's delta gate.
    float pre_cur[7], pre_nxt[7];
    {
        const int ev0 = ev_row[0];
#pragma unroll
        for (int g = 0; g < 7; ++g) pre_cur[g] = pre_emb[ev0 * GG + g * 64 + e];
    }
    int   evn    = ev_row[1];
    float dt_cur = dt_row[1];

    float c = 0.f, cb = 0.f;
    __syncthreads();

    for (int t = 0; t < TT; ++t) {
        // issue next-step prefetches first so latency overlaps this step
#pragma unroll
        for (int g = 0; g < 7; ++g) pre_nxt[g] = pre_emb[evn * GG + g * 64 + e];
        int t2 = t + 2; if (t2 > T2 - 1) t2 = T2 - 1;
        const int   ev_new = ev_row[t2];
        const float dt_nxt = dt_row[t2];

        // ---- A fragments: h_{t-1} as bf16 hi/lo (rows replicated) ----
        const int rb = t & 1;
        const bf16x8 Ahi0 = *(const bf16x8*)&hs_hi[rb][q * 8];
        const bf16x8 Ahi1 = *(const bf16x8*)&hs_hi[rb][32 + q * 8];
        const bf16x8 Alo0 = *(const bf16x8*)&hs_lo[rb][q * 8];
        const bf16x8 Alo1 = *(const bf16x8*)&hs_lo[rb][32 + q * 8];

        // ---- 7 gate pre-activations via MFMA (C-in = pre, all rows) ----
        // two independent 3-deep chains per gate to halve MFMA latency chain
        float gate[7];
#pragma unroll
        for (int g = 0; g < 7; ++g) {
            const float p = pre_cur[g];
            f32x4 accA = { p, p, p, p };
            f32x4 accB = { 0.f, 0.f, 0.f, 0.f };
            accA = __builtin_amdgcn_mfma_f32_16x16x32_bf16(Ahi0, Bhi[g][0], accA, 0, 0, 0);
            accB = __builtin_amdgcn_mfma_f32_16x16x32_bf16(Ahi1, Bhi[g][1], accB, 0, 0, 0);
            accA = __builtin_amdgcn_mfma_f32_16x16x32_bf16(Alo0, Bhi[g][0], accA, 0, 0, 0);
            accB = __builtin_amdgcn_mfma_f32_16x16x32_bf16(Alo1, Bhi[g][1], accB, 0, 0, 0);
            accA = __builtin_amdgcn_mfma_f32_16x16x32_bf16(Ahi0, Blo[g][0], accA, 0, 0, 0);
            accB = __builtin_amdgcn_mfma_f32_16x16x32_bf16(Ahi1, Blo[g][1], accB, 0, 0, 0);
            gate[g] = accA[0] + accB[0];
        }

        // ---- activations + state update (lane-local, all lanes valid) ----
        const float i_g  = sigmoid_fast(gate[0]);
        const float f_g  = sigmoid_fast(gate[1]);
        const float z_g  = tanh_fast(gate[2]);
        const float o_g  = sigmoid_fast(gate[3]);
        const float ib_g = sigmoid_fast(gate[4]);
        const float fb_g = sigmoid_fast(gate[5]);
        const float ed   = expn_fast(-softplus_fast(gate[6]) * dt_cur);

        const float ci  = fmaf(f_g, c, i_g * z_g);
        const float cbi = fmaf(fb_g, cb, ib_g * z_g);
        const float cn  = fmaf(ci - cbi, ed, cbi);
        const float h   = o_g * tanh_fast(cn);
        c  = cn;
        cb = cbi;

        // ---- publish h: bf16 hi/lo to LDS (next iter), f32 to global ----
        const unsigned short hhi = bf16_rne(h);
        const float          hre = h - bf16_to_f(hhi);
        const unsigned short hlo = bf16_rne(hre);
        const int wbuf = (t + 1) & 1;
        if (l < 16) {
            hs_hi[wbuf][e] = hhi;
            hs_lo[wbuf][e] = hlo;
            out_row[(size_t)t * KK + e] = h;
        }

#pragma unroll
        for (int g = 0; g < 7; ++g) pre_cur[g] = pre_nxt[g];
        evn    = ev_new;
        dt_cur = dt_nxt;
        __syncthreads();
    }
}

// out[b,t,k] = softplus(dot(h[b,t,:], oe[k,:])), h in out[b,t,0:64].
// No LDS, no barrier: each tt row is loaded (broadcast, L2-resident) and
// stored by ONE wave; the stores data-depend on all loads of that row, so
// the in-place overwrite of h is safe. Wave v handles tt = v, v+4, ...
// Lane owns cols {lane, 64+lane} (second masked to <100).
__launch_bounds__(256)
__global__ void logits_kernel(const float* __restrict__ oe,
                              float* __restrict__ out) {
    const int b    = blockIdx.x;
    const int t0   = blockIdx.y * TCHUNK;
    const int nt   = (TT - t0 < TCHUNK) ? (TT - t0) : TCHUNK;
    const int tid  = threadIdx.x;
    const int wv   = tid >> 6;
    const int lane = tid & 63;

    const int  c1     = (lane < KK - HH) ? (HH + lane) : (KK - 1);
    const bool has_c1 = (lane < KK - HH);

    float wk0[HH], wk1[HH];
#pragma unroll
    for (int qq = 0; qq < HH / 4; ++qq) {
        ((float4*)wk0)[qq] = ((const float4*)(oe + lane * HH))[qq];
        ((float4*)wk1)[qq] = ((const float4*)(oe + c1 * HH))[qq];
    }

    for (int tt = wv; tt < nt; tt += 4) {
        float* row = out + ((size_t)b * TT + t0 + tt) * KK;
        float a0 = 0.f, a1 = 0.f, a2 = 0.f, a3 = 0.f;
        float b0 = 0.f, b1 = 0.f, b2 = 0.f, b3 = 0.f;
#pragma unroll
        for (int qq = 0; qq < HH / 4; ++qq) {
            const float4 hv = ((const float4*)row)[qq];
            a0 = fmaf(hv.x, wk0[4 * qq + 0], a0);
            a1 = fmaf(hv.y, wk0[4 * qq + 1], a1);
            a2 = fmaf(hv.z, wk0[4 * qq + 2], a2);
            a3 = fmaf(hv.w, wk0[4 * qq + 3], a3);
            b0 = fmaf(hv.x, wk1[4 * qq + 0], b0);
            b1 = fmaf(hv.y, wk1[4 * qq + 1], b1);
            b2 = fmaf(hv.z, wk1[4 * qq + 2], b2);
            b3 = fmaf(hv.w, wk1[4 * qq + 3], b3);
        }
        const float lg0 = (a0 + a1) + (a2 + a3);
        const float lg1 = (b0 + b1) + (b2 + b3);
        row[lane] = softplus_fast(lg0);
        if (has_c1) row[HH + lane] = softplus_fast(lg1);
    }
}

extern "C" void kernel_launch(void* const* d_in, const int* in_sizes, int n_in,
                              void* d_out, int out_size, void* d_ws, size_t ws_size,
                              hipStream_t stream) {
    const int*   event  = (const int*)d_in[0];
    const float* dtime  = (const float*)d_in[1];
    const float* in_emb = (const float*)d_in[2];
    const float* Wx     = (const float*)d_in[3];
    const float* Wh     = (const float*)d_in[4];
    const float* bias   = (const float*)d_in[5];
    const float* oe     = (const float*)d_in[6];
    float*       out    = (float*)d_out;

    float* pre_emb = (float*)d_ws;  // 103*448*4 = 184,576 bytes

    pre_emb_kernel<<<NE, GG, 0, stream>>>(in_emb, Wx, bias, pre_emb);
    scan_kernel<<<BB, 256, 0, stream>>>(event, dtime, pre_emb, Wh, out);
    logits_kernel<<<dim3(BB, NCHUNK), 256, 0, stream>>>(oe, out);
}

// Round 4
// 1739.240 us; speedup vs baseline: 1.0945x; 1.0945x over previous
//
#include <hip/hip_runtime.h>
#include <math.h>

#define BB 128
#define T2 2050
#define TT 2049
#define HH 64
#define GG 448   // 7*H
#define KK 100
#define NE 103   // K+3

#define LOG2E 1.44269504088896340736f
#define LN2   0.69314718055994530942f

typedef short bf16x8 __attribute__((ext_vector_type(8)));  // 8 bf16 bit-patterns (4 VGPRs)
typedef float f32x4  __attribute__((ext_vector_type(4)));

// ---- fast transcendentals (native v_exp_f32 / v_log_f32 / v_rcp_f32) ----
__device__ __forceinline__ float frcp(float x) { return __builtin_amdgcn_rcpf(x); }

__device__ __forceinline__ float sigmoid_fast(float x) {
    return frcp(1.f + exp2f(-x * LOG2E));
}
__device__ __forceinline__ float tanh_fast(float x) {
    float e = exp2f(x * (2.f * LOG2E));
    return 1.f - 2.f * frcp(1.f + e);
}
__device__ __forceinline__ float softplus_fast(float x) {
    float t = exp2f(-fabsf(x) * LOG2E);
    return fmaxf(x, 0.f) + LN2 * log2f(1.f + t);
}

// ---- bf16 split helpers (RNE) ----
__device__ __forceinline__ unsigned short bf16_rne(float f) {
    unsigned int u = __builtin_bit_cast(unsigned int, f);
    unsigned int r = u + 0x7FFFu + ((u >> 16) & 1u);
    return (unsigned short)(r >> 16);
}
__device__ __forceinline__ float bf16_to_f(unsigned short s) {
    unsigned int u = ((unsigned int)s) << 16;
    return __builtin_bit_cast(float, u);
}

// pre_emb[e][t] = sum_k in_emb[e][k] * Wx[k][t] + bias[t]   (103 x 448)
__global__ void pre_emb_kernel(const float* __restrict__ in_emb,
                               const float* __restrict__ Wx,
                               const float* __restrict__ bias,
                               float* __restrict__ pre_emb) {
    int e = blockIdx.x;
    int t = threadIdx.x;
    float acc = bias[t];
#pragma unroll
    for (int k = 0; k < HH; ++k)
        acc = fmaf(in_emb[e * HH + k], Wx[k * GG + t], acc);
    pre_emb[e * GG + t] = acc;
}

// Raw barrier: fence LDS only (lgkmcnt), leave global loads/stores in flight
// across the barrier (they are never consumed by another wave). This removes
// the ~300-400cy vmcnt(0) store-drain __syncthreads() would impose per step.
__device__ __forceinline__ void step_barrier() {
    __builtin_amdgcn_sched_barrier(0);
    asm volatile("s_waitcnt lgkmcnt(0)" ::: "memory");
    __builtin_amdgcn_s_barrier();
    __builtin_amdgcn_sched_barrier(0);
}

// One block per batch row; 8 waves (4 mat + 4 logit), ONE raw barrier/step.
//  - mat wave w (0..3) owns elements e in [16w,16w+16): 7 gates x 6 MFMA
//    (split-bf16 hi/lo, A rows replicated), lane-local state update, h
//    published as bf16 hi/lo into double-buffered LDS.
//  - logit wave (4..7) owns 2 (resp 1) groups of 16 out_emb columns; reads
//    the same h LDS buffers (one step behind), 6 MFMA/group against
//    register-resident oe hi/lo fragments, softplus, stores directly to out.
//    => no h-history round-trip, no separate logits kernel.
__launch_bounds__(512, 1)
__global__ void scan_kernel(const int* __restrict__ event,
                            const float* __restrict__ dtime,
                            const float* __restrict__ pre_emb,
                            const float* __restrict__ Wh,
                            const float* __restrict__ oe,
                            float* __restrict__ out) {
    const int b   = blockIdx.x;
    const int tid = threadIdx.x;
    const int w   = tid >> 6;     // wave 0..7
    const int l   = tid & 63;     // lane
    const int q   = l >> 4;       // quarter 0..3
    const int m   = l & 15;       // sub-lane 0..15

    __shared__ __align__(16) unsigned short hs_hi[2][HH];
    __shared__ __align__(16) unsigned short hs_lo[2][HH];

    const bool is_mat = (w < 4);
    const int  e      = ((w & 3) << 4) | m;   // mat: element owned

    const int*   ev_row  = event + b * T2;
    const float* dt_row  = dtime + b * T2;
    float*       out_row = out + (size_t)b * TT * KK;

    const f32x4 Z = { 0.f, 0.f, 0.f, 0.f };

    // ---- per-wave register weight fragments ----
    bf16x8 Bhi[7][2], Blo[7][2];      // mat: Wh columns (hi/lo split)
    bf16x8 Phi[2][2], Plo[2][2];      // logit: oe columns (hi/lo split)
    const int jw  = w - 4;            // logit wave index 0..3
    const int G0  = 2 * jw;           // first owned group
    const bool has1 = (2 * jw + 1) < 7;
    const int G1  = has1 ? (2 * jw + 1) : G0;

    if (is_mat) {
#pragma unroll
        for (int g = 0; g < 7; ++g) {
#pragma unroll
            for (int kh = 0; kh < 2; ++kh) {
                const int col = g * 64 + e;
                bf16x8 bh, bl;
#pragma unroll
                for (int j = 0; j < 8; ++j) {
                    const int k = kh * 32 + q * 8 + j;
                    const float v = Wh[k * GG + col];
                    const unsigned short hi = bf16_rne(v);
                    bh[j] = (short)hi;
                    bl[j] = (short)bf16_rne(v - bf16_to_f(hi));
                }
                Bhi[g][kh] = bh;
                Blo[g][kh] = bl;
            }
        }
    } else {
#pragma unroll
        for (int s = 0; s < 2; ++s) {
            const int Gs  = s ? G1 : G0;
            int col = Gs * 16 + m;
            if (col > KK - 1) col = KK - 1;   // clamp pad cols (stores masked)
#pragma unroll
            for (int kh = 0; kh < 2; ++kh) {
                bf16x8 bh, bl;
#pragma unroll
                for (int j = 0; j < 8; ++j) {
                    const int k = kh * 32 + q * 8 + j;
                    const float v = oe[col * HH + k];
                    const unsigned short hi = bf16_rne(v);
                    bh[j] = (short)hi;
                    bl[j] = (short)bf16_rne(v - bf16_to_f(hi));
                }
                Phi[s][kh] = bh;
                Plo[s][kh] = bl;
            }
        }
    }

    // ---- mat-wave scan pipeline state ----
    float pre_cur[7];
    int   evn    = 0;
    float dt_cur = 0.f;
    float c = 0.f, cb = 0.f;
    if (is_mat) {
        const int ev0 = __builtin_amdgcn_readfirstlane(ev_row[0]);
        const float* pb0 = pre_emb + ev0 * GG;
#pragma unroll
        for (int g = 0; g < 7; ++g) pre_cur[g] = pb0[g * 64 + e];
        evn    = __builtin_amdgcn_readfirstlane(ev_row[1]);
        dt_cur = dt_row[1];
    }

    if (tid < HH) { hs_hi[0][tid] = 0; hs_lo[0][tid] = 0; }
    __syncthreads();

    // gate order: start the longest dependency chains (delta, z) first
    constexpr int GORD[7] = { 6, 2, 0, 1, 4, 5, 3 };

    for (int t = 0; t < TT; ++t) {
        const int rb = t & 1;
        if (is_mat) {
            // prefetch next step's pre row (SGPR base, fire-and-forget)
            const float* pb = pre_emb + evn * GG;
            float pre_nxt[7];
#pragma unroll
            for (int g = 0; g < 7; ++g) pre_nxt[g] = pb[g * 64 + e];
            int t2 = t + 2; if (t2 > T2 - 1) t2 = T2 - 1;
            const int   ev_new = __builtin_amdgcn_readfirstlane(ev_row[t2]);
            const float dt_nxt = dt_row[t2];

            // A fragments: h_{t-1} hi/lo, rows replicated
            const bf16x8 Ahi0 = *(const bf16x8*)&hs_hi[rb][q * 8];
            const bf16x8 Ahi1 = *(const bf16x8*)&hs_hi[rb][32 + q * 8];
            const bf16x8 Alo0 = *(const bf16x8*)&hs_lo[rb][q * 8];
            const bf16x8 Alo1 = *(const bf16x8*)&hs_lo[rb][32 + q * 8];

            float gate[7];
#pragma unroll
            for (int gg = 0; gg < 7; ++gg) {
                const int g = GORD[gg];
                f32x4 aP = __builtin_amdgcn_mfma_f32_16x16x32_bf16(Ahi0, Bhi[g][0], Z, 0, 0, 0);
                f32x4 aQ = __builtin_amdgcn_mfma_f32_16x16x32_bf16(Ahi1, Bhi[g][1], Z, 0, 0, 0);
                aP = __builtin_amdgcn_mfma_f32_16x16x32_bf16(Alo0, Bhi[g][0], aP, 0, 0, 0);
                aQ = __builtin_amdgcn_mfma_f32_16x16x32_bf16(Alo1, Bhi[g][1], aQ, 0, 0, 0);
                aP = __builtin_amdgcn_mfma_f32_16x16x32_bf16(Ahi0, Blo[g][0], aP, 0, 0, 0);
                aQ = __builtin_amdgcn_mfma_f32_16x16x32_bf16(Ahi1, Blo[g][1], aQ, 0, 0, 0);
                gate[g] = pre_cur[g] + (aP[0] + aQ[0]);
            }

            // ed = exp(-softplus(gd)*dt) = 2^(-dt*log2(1+2^(gd*log2e)))
            const float ed   = exp2f(-dt_cur * log2f(1.f + exp2f(gate[6] * LOG2E)));
            const float z_g  = tanh_fast(gate[2]);
            const float i_g  = sigmoid_fast(gate[0]);
            const float f_g  = sigmoid_fast(gate[1]);
            const float ib_g = sigmoid_fast(gate[4]);
            const float fb_g = sigmoid_fast(gate[5]);
            const float o_g  = sigmoid_fast(gate[3]);

            const float ci  = fmaf(f_g, c, i_g * z_g);
            const float cbi = fmaf(fb_g, cb, ib_g * z_g);
            const float cn  = fmaf(ci - cbi, ed, cbi);
            const float h   = o_g * tanh_fast(cn);
            c  = cn;
            cb = cbi;

            const unsigned short hhi = bf16_rne(h);
            const unsigned short hlo = bf16_rne(h - bf16_to_f(hhi));
            const int wb = (t + 1) & 1;
            if (l < 32) {   // q0 lanes publish hi, q1 lanes publish lo
                unsigned short* p = (l < 16) ? &hs_hi[wb][e] : &hs_lo[wb][e];
                *p = (l < 16) ? hhi : hlo;
            }

#pragma unroll
            for (int g = 0; g < 7; ++g) pre_cur[g] = pre_nxt[g];
            evn    = ev_new;
            dt_cur = dt_nxt;
        } else if (t > 0) {
            // logits of h_{t-1} (in buf rb), direct to out; no drain needed
            const bf16x8 Ahi0 = *(const bf16x8*)&hs_hi[rb][q * 8];
            const bf16x8 Ahi1 = *(const bf16x8*)&hs_hi[rb][32 + q * 8];
            const bf16x8 Alo0 = *(const bf16x8*)&hs_lo[rb][q * 8];
            const bf16x8 Alo1 = *(const bf16x8*)&hs_lo[rb][32 + q * 8];

            float lg[2];
#pragma unroll
            for (int s = 0; s < 2; ++s) {
                f32x4 aP = __builtin_amdgcn_mfma_f32_16x16x32_bf16(Ahi0, Phi[s][0], Z, 0, 0, 0);
                f32x4 aQ = __builtin_amdgcn_mfma_f32_16x16x32_bf16(Ahi1, Phi[s][1], Z, 0, 0, 0);
                aP = __builtin_amdgcn_mfma_f32_16x16x32_bf16(Alo0, Phi[s][0], aP, 0, 0, 0);
                aQ = __builtin_amdgcn_mfma_f32_16x16x32_bf16(Alo1, Phi[s][1], aQ, 0, 0, 0);
                aP = __builtin_amdgcn_mfma_f32_16x16x32_bf16(Ahi0, Plo[s][0], aP, 0, 0, 0);
                aQ = __builtin_amdgcn_mfma_f32_16x16x32_bf16(Ahi1, Plo[s][1], aQ, 0, 0, 0);
                lg[s] = aP[0] + aQ[0];
            }
            if (q == 0) {
                const int col0 = G0 * 16 + m;
                if (col0 < KK)
                    out_row[(size_t)(t - 1) * KK + col0] = softplus_fast(lg[0]);
                const int col1 = G1 * 16 + m;
                if (has1 && col1 < KK)
                    out_row[(size_t)(t - 1) * KK + col1] = softplus_fast(lg[1]);
            }
        }
        step_barrier();
    }

    // tail: logits of h_{TT-1} (written at t=TT-1 into buf[TT&1])
    if (!is_mat) {
        const int rb = TT & 1;
        const bf16x8 Ahi0 = *(const bf16x8*)&hs_hi[rb][q * 8];
        const bf16x8 Ahi1 = *(const bf16x8*)&hs_hi[rb][32 + q * 8];
        const bf16x8 Alo0 = *(const bf16x8*)&hs_lo[rb][q * 8];
        const bf16x8 Alo1 = *(const bf16x8*)&hs_lo[rb][32 + q * 8];

        float lg[2];
#pragma unroll
        for (int s = 0; s < 2; ++s) {
            f32x4 aP = __builtin_amdgcn_mfma_f32_16x16x32_bf16(Ahi0, Phi[s][0], Z, 0, 0, 0);
            f32x4 aQ = __builtin_amdgcn_mfma_f32_16x16x32_bf16(Ahi1, Phi[s][1], Z, 0, 0, 0);
            aP = __builtin_amdgcn_mfma_f32_16x16x32_bf16(Alo0, Phi[s][0], aP, 0, 0, 0);
            aQ = __builtin_amdgcn_mfma_f32_16x16x32_bf16(Alo1, Phi[s][1], aQ, 0, 0, 0);
            aP = __builtin_amdgcn_mfma_f32_16x16x32_bf16(Ahi0, Plo[s][0], aP, 0, 0, 0);
            aQ = __builtin_amdgcn_mfma_f32_16x16x32_bf16(Ahi1, Plo[s][1], aQ, 0, 0, 0);
            lg[s] = aP[0] + aQ[0];
        }
        if (q == 0) {
            const int col0 = G0 * 16 + m;
            if (col0 < KK)
                out_row[(size_t)(TT - 1) * KK + col0] = softplus_fast(lg[0]);
            const int col1 = G1 * 16 + m;
            if (has1 && col1 < KK)
                out_row[(size_t)(TT - 1) * KK + col1] = softplus_fast(lg[1]);
        }
    }
}

extern "C" void kernel_launch(void* const* d_in, const int* in_sizes, int n_in,
                              void* d_out, int out_size, void* d_ws, size_t ws_size,
                              hipStream_t stream) {
    const int*   event  = (const int*)d_in[0];
    const float* dtime  = (const float*)d_in[1];
    const float* in_emb = (const float*)d_in[2];
    const float* Wx     = (const float*)d_in[3];
    const float* Wh     = (const float*)d_in[4];
    const float* bias   = (const float*)d_in[5];
    const float* oe     = (const float*)d_in[6];
    float*       out    = (float*)d_out;

    float* pre_emb = (float*)d_ws;  // 103*448*4 = 184,576 bytes

    pre_emb_kernel<<<NE, GG, 0, stream>>>(in_emb, Wx, bias, pre_emb);
    scan_kernel<<<BB, 512, 0, stream>>>(event, dtime, pre_emb, Wh, oe, out);
}

// Round 5
// 1680.069 us; speedup vs baseline: 1.1331x; 1.0352x over previous
//
#include <hip/hip_runtime.h>
#include <math.h>

#define BB 128
#define T2 2050
#define TT 2049
#define HH 64
#define GG 448   // 7*H
#define KK 100
#define NE 103   // K+3
#define NSTAGE 2056  // staged ev/dt length (TT + pipeline pad)

#define LOG2E 1.44269504088896340736f
#define LN2   0.69314718055994530942f

typedef short bf16x8 __attribute__((ext_vector_type(8)));  // 8 bf16 bit-patterns (4 VGPRs)
typedef float f32x4  __attribute__((ext_vector_type(4)));

// ---- fast transcendentals (native v_exp_f32 / v_log_f32 / v_rcp_f32) ----
__device__ __forceinline__ float frcp(float x) { return __builtin_amdgcn_rcpf(x); }

__device__ __forceinline__ float sigmoid_fast(float x) {
    return frcp(1.f + exp2f(-x * LOG2E));
}
__device__ __forceinline__ float tanh_fast(float x) {
    float e = exp2f(x * (2.f * LOG2E));
    return 1.f - 2.f * frcp(1.f + e);
}
__device__ __forceinline__ float softplus_fast(float x) {
    float t = exp2f(-fabsf(x) * LOG2E);
    return fmaxf(x, 0.f) + LN2 * log2f(1.f + t);
}

// ---- bf16 split helpers (RNE) ----
__device__ __forceinline__ unsigned short bf16_rne(float f) {
    unsigned int u = __builtin_bit_cast(unsigned int, f);
    unsigned int r = u + 0x7FFFu + ((u >> 16) & 1u);
    return (unsigned short)(r >> 16);
}
__device__ __forceinline__ float bf16_to_f(unsigned short s) {
    unsigned int u = ((unsigned int)s) << 16;
    return __builtin_bit_cast(float, u);
}

// pre_emb[e][t] = sum_k in_emb[e][k] * Wx[k][t] + bias[t]   (103 x 448)
__global__ void pre_emb_kernel(const float* __restrict__ in_emb,
                               const float* __restrict__ Wx,
                               const float* __restrict__ bias,
                               float* __restrict__ pre_emb) {
    int e = blockIdx.x;
    int t = threadIdx.x;
    float acc = bias[t];
#pragma unroll
    for (int k = 0; k < HH; ++k)
        acc = fmaf(in_emb[e * HH + k], Wx[k * GG + t], acc);
    pre_emb[e * GG + t] = acc;
}

// Raw barrier: fence LDS only (lgkmcnt); global loads/stores stay in flight.
__device__ __forceinline__ void step_barrier() {
    __builtin_amdgcn_sched_barrier(0);
    asm volatile("s_waitcnt lgkmcnt(0)" ::: "memory");
    __builtin_amdgcn_s_barrier();
    __builtin_amdgcn_sched_barrier(0);
}

// One block per batch row; 8 waves (4 mat + 4 logit), one raw barrier/step.
// vs R4: (1) t-loop unrolled x2 with per-parity static prefetch buffers so
// every global load (pre_emb row) is consumed ~2 steps (~1300cy) after issue
// and NO in-loop vmcnt wait can hit the critical chain; (2) ev/dt staged in
// LDS once (per-step scalar pipeline = 2 broadcast ds_reads, 2-step slack);
// (3) mat waves run at s_setprio(1): logit waves yield issue slots.
__launch_bounds__(512, 1)
__global__ void scan_kernel(const int* __restrict__ event,
                            const float* __restrict__ dtime,
                            const float* __restrict__ pre_emb,
                            const float* __restrict__ Wh,
                            const float* __restrict__ oe,
                            float* __restrict__ out) {
    const int b   = blockIdx.x;
    const int tid = threadIdx.x;
    const int w   = tid >> 6;     // wave 0..7
    const int l   = tid & 63;     // lane
    const int q   = l >> 4;       // quarter 0..3
    const int m   = l & 15;       // sub-lane 0..15

    __shared__ __align__(16) unsigned short hs_hi[2][HH];
    __shared__ __align__(16) unsigned short hs_lo[2][HH];
    __shared__ int   evoff_s[NSTAGE];   // pre_emb row offset (float units)
    __shared__ float dtl_s[NSTAGE];

    const bool is_mat = (w < 4);
    const int  e      = ((w & 3) << 4) | m;   // mat: element owned

    const int*   ev_row  = event + b * T2;
    const float* dt_row  = dtime + b * T2;
    float*       out_row = out + (size_t)b * TT * KK;

    const f32x4 Z = { 0.f, 0.f, 0.f, 0.f };
    constexpr int GORD[7] = { 6, 2, 0, 1, 4, 5, 3 };

    // ---- stage ev (as row offsets) and dt into LDS (one-time) ----
    for (int i = tid; i < NSTAGE; i += 512) {
        const int idx = (i < T2) ? i : (T2 - 1);
        evoff_s[i] = ev_row[idx] * GG;
        dtl_s[i]   = dt_row[idx];
    }

    // ---- per-wave register weight fragments ----
    bf16x8 Bhi[7][2], Blo[7][2];      // mat: Wh columns (hi/lo split)
    bf16x8 Phi[2][2], Plo[2][2];      // logit: oe columns (hi/lo split)
    const int jw    = w - 4;          // logit wave index 0..3
    const int G0    = 2 * jw;
    const bool has1 = (2 * jw + 1) < 7;
    const int G1    = has1 ? (2 * jw + 1) : G0;

    if (is_mat) {
#pragma unroll
        for (int g = 0; g < 7; ++g) {
#pragma unroll
            for (int kh = 0; kh < 2; ++kh) {
                const int col = g * 64 + e;
                bf16x8 bh, bl;
#pragma unroll
                for (int j = 0; j < 8; ++j) {
                    const int k = kh * 32 + q * 8 + j;
                    const float v = Wh[k * GG + col];
                    const unsigned short hi = bf16_rne(v);
                    bh[j] = (short)hi;
                    bl[j] = (short)bf16_rne(v - bf16_to_f(hi));
                }
                Bhi[g][kh] = bh;
                Blo[g][kh] = bl;
            }
        }
    } else {
#pragma unroll
        for (int s = 0; s < 2; ++s) {
            const int Gs = s ? G1 : G0;
            int col = Gs * 16 + m;
            if (col > KK - 1) col = KK - 1;   // clamp pad cols (stores masked)
#pragma unroll
            for (int kh = 0; kh < 2; ++kh) {
                bf16x8 bh, bl;
#pragma unroll
                for (int j = 0; j < 8; ++j) {
                    const int k = kh * 32 + q * 8 + j;
                    const float v = oe[col * HH + k];
                    const unsigned short hi = bf16_rne(v);
                    bh[j] = (short)hi;
                    bl[j] = (short)bf16_rne(v - bf16_to_f(hi));
                }
                Phi[s][kh] = bh;
                Plo[s][kh] = bl;
            }
        }
    }

    if (tid < HH) { hs_hi[0][tid] = 0; hs_lo[0][tid] = 0; }
    __syncthreads();

    // ---- mat prologue: fill both parity pipelines (steps 0 and 1) ----
    float preE[7], preO[7];
    int   offE = 0, offO = 0;
    float dtE = 0.f, dtO = 0.f;
    if (is_mat) {
        const int o0 = evoff_s[0], o1 = evoff_s[1];
#pragma unroll
        for (int g = 0; g < 7; ++g) {
            preE[g] = pre_emb[o0 + g * 64 + e];
            preO[g] = pre_emb[o1 + g * 64 + e];
        }
        offE = evoff_s[2];   // used at t=0 to prefetch step 2
        offO = evoff_s[3];   // used at t=1 to prefetch step 3
        dtE  = dtl_s[1];     // step t uses dt_row[t+1]
        dtO  = dtl_s[2];
    }

    // logit-wave store bookkeeping
    const int  col0   = G0 * 16 + m;
    const int  col1   = G1 * 16 + m;
    const bool c0ok   = (col0 < KK);
    const bool c1ok   = has1 && (col1 < KK);
    float*     outP   = out_row;      // row t-1 pointer, advanced per store

// ---- mat step: consume parity buffers, refill 2 steps ahead ----
#define MAT_STEP(RB, WB, PRE, OFF, DTV, TIDX)                                   \
    {                                                                           \
        float pc[7];                                                            \
        _Pragma("unroll") for (int g = 0; g < 7; ++g) pc[g] = PRE[g];           \
        const float* pb = pre_emb + OFF;                                        \
        _Pragma("unroll") for (int g = 0; g < 7; ++g) PRE[g] = pb[g * 64 + e];  \
        OFF = evoff_s[(TIDX) + 4];                                              \
        const float dtc = DTV;                                                  \
        DTV = dtl_s[(TIDX) + 3];                                                \
        const bf16x8 Ahi0 = *(const bf16x8*)&hs_hi[RB][q * 8];                  \
        const bf16x8 Ahi1 = *(const bf16x8*)&hs_hi[RB][32 + q * 8];             \
        const bf16x8 Alo0 = *(const bf16x8*)&hs_lo[RB][q * 8];                  \
        const bf16x8 Alo1 = *(const bf16x8*)&hs_lo[RB][32 + q * 8];             \
        float gate[7];                                                          \
        _Pragma("unroll") for (int gg = 0; gg < 7; ++gg) {                      \
            const int g = GORD[gg];                                             \
            f32x4 aP = __builtin_amdgcn_mfma_f32_16x16x32_bf16(Ahi0, Bhi[g][0], Z, 0, 0, 0); \
            f32x4 aQ = __builtin_amdgcn_mfma_f32_16x16x32_bf16(Ahi1, Bhi[g][1], Z, 0, 0, 0); \
            aP = __builtin_amdgcn_mfma_f32_16x16x32_bf16(Alo0, Bhi[g][0], aP, 0, 0, 0); \
            aQ = __builtin_amdgcn_mfma_f32_16x16x32_bf16(Alo1, Bhi[g][1], aQ, 0, 0, 0); \
            aP = __builtin_amdgcn_mfma_f32_16x16x32_bf16(Ahi0, Blo[g][0], aP, 0, 0, 0); \
            aQ = __builtin_amdgcn_mfma_f32_16x16x32_bf16(Ahi1, Blo[g][1], aQ, 0, 0, 0); \
            gate[g] = pc[g] + (aP[0] + aQ[0]);                                  \
        }                                                                       \
        const float ed   = exp2f(-dtc * log2f(1.f + exp2f(gate[6] * LOG2E)));   \
        const float z_g  = tanh_fast(gate[2]);                                  \
        const float i_g  = sigmoid_fast(gate[0]);                               \
        const float f_g  = sigmoid_fast(gate[1]);                               \
        const float ib_g = sigmoid_fast(gate[4]);                               \
        const float fb_g = sigmoid_fast(gate[5]);                               \
        const float o_g  = sigmoid_fast(gate[3]);                               \
        const float ci  = fmaf(f_g, c, i_g * z_g);                              \
        const float cbi = fmaf(fb_g, cb, ib_g * z_g);                           \
        const float cn  = fmaf(ci - cbi, ed, cbi);                              \
        const float h   = o_g * tanh_fast(cn);                                  \
        c  = cn;                                                                \
        cb = cbi;                                                               \
        const unsigned short hhi = bf16_rne(h);                                 \
        const unsigned short hlo = bf16_rne(h - bf16_to_f(hhi));                \
        if (l < 32) {                                                           \
            unsigned short* p = (l < 16) ? &hs_hi[WB][e] : &hs_lo[WB][e];       \
            *p = (l < 16) ? hhi : hlo;                                          \
        }                                                                       \
    }

// ---- logit step: logits of h held in hs[RB], store to row (outP) ----
#define LOGIT_STEP(RB, DO_STORE)                                                \
    {                                                                           \
        const bf16x8 Ahi0 = *(const bf16x8*)&hs_hi[RB][q * 8];                  \
        const bf16x8 Ahi1 = *(const bf16x8*)&hs_hi[RB][32 + q * 8];             \
        const bf16x8 Alo0 = *(const bf16x8*)&hs_lo[RB][q * 8];                  \
        const bf16x8 Alo1 = *(const bf16x8*)&hs_lo[RB][32 + q * 8];             \
        float lg[2];                                                            \
        _Pragma("unroll") for (int s = 0; s < 2; ++s) {                         \
            f32x4 aP = __builtin_amdgcn_mfma_f32_16x16x32_bf16(Ahi0, Phi[s][0], Z, 0, 0, 0); \
            f32x4 aQ = __builtin_amdgcn_mfma_f32_16x16x32_bf16(Ahi1, Phi[s][1], Z, 0, 0, 0); \
            aP = __builtin_amdgcn_mfma_f32_16x16x32_bf16(Alo0, Phi[s][0], aP, 0, 0, 0); \
            aQ = __builtin_amdgcn_mfma_f32_16x16x32_bf16(Alo1, Phi[s][1], aQ, 0, 0, 0); \
            aP = __builtin_amdgcn_mfma_f32_16x16x32_bf16(Ahi0, Plo[s][0], aP, 0, 0, 0); \
            aQ = __builtin_amdgcn_mfma_f32_16x16x32_bf16(Ahi1, Plo[s][1], aQ, 0, 0, 0); \
            lg[s] = aP[0] + aQ[0];                                              \
        }                                                                       \
        if (DO_STORE) {                                                         \
            if (q == 0) {                                                       \
                if (c0ok) outP[col0] = softplus_fast(lg[0]);                    \
                if (c1ok) outP[col1] = softplus_fast(lg[1]);                    \
            }                                                                   \
            outP += KK;                                                         \
        }                                                                       \
    }

    float c = 0.f, cb = 0.f;
    if (is_mat) __builtin_amdgcn_s_setprio(1);

    // main loop: 1024 double-steps cover t = 0..2047
    for (int tp = 0; tp < (TT - 1) / 2; ++tp) {
        const int te = 2 * tp;
        if (is_mat) { MAT_STEP(0, 1, preE, offE, dtE, te) }
        else        { LOGIT_STEP(0, (tp > 0)) }
        step_barrier();
        if (is_mat) { MAT_STEP(1, 0, preO, offO, dtO, te + 1) }
        else        { LOGIT_STEP(1, true) }
        step_barrier();
    }
    // tail step t = 2048 (even: read hs[0], write hs[1])
    if (is_mat) { MAT_STEP(0, 1, preE, offE, dtE, TT - 1) }
    else        { LOGIT_STEP(0, true) }
    step_barrier();
    if (is_mat) __builtin_amdgcn_s_setprio(0);

    // final logits of h_{TT-1} (in hs[1]) -> row TT-1
    if (!is_mat) { LOGIT_STEP(1, true) }

#undef MAT_STEP
#undef LOGIT_STEP
}

extern "C" void kernel_launch(void* const* d_in, const int* in_sizes, int n_in,
                              void* d_out, int out_size, void* d_ws, size_t ws_size,
                              hipStream_t stream) {
    const int*   event  = (const int*)d_in[0];
    const float* dtime  = (const float*)d_in[1];
    const float* in_emb = (const float*)d_in[2];
    const float* Wx     = (const float*)d_in[3];
    const float* Wh     = (const float*)d_in[4];
    const float* bias   = (const float*)d_in[5];
    const float* oe     = (const float*)d_in[6];
    float*       out    = (float*)d_out;

    float* pre_emb = (float*)d_ws;  // 103*448*4 = 184,576 bytes

    pre_emb_kernel<<<NE, GG, 0, stream>>>(in_emb, Wx, bias, pre_emb);
    scan_kernel<<<BB, 512, 0, stream>>>(event, dtime, pre_emb, Wh, oe, out);
}

// Round 6
// 1394.516 us; speedup vs baseline: 1.3651x; 1.2048x over previous
//
#include <hip/hip_runtime.h>
#include <math.h>

#define BB 128
#define T2 2050
#define TT 2049
#define HH 64
#define GG 448   // 7*H
#define KK 100
#define NE 103   // K+3
#define NSTAGE 2056  // staged ev/dt length (TT + pipeline pad)
#define NTHREADS 576 // 9 waves: 7 gate + 2 logit

#define LOG2E 1.44269504088896340736f
#define LN2   0.69314718055994530942f

// ---- fast transcendentals (native v_exp_f32 / v_log_f32 / v_rcp_f32) ----
__device__ __forceinline__ float frcp(float x) { return __builtin_amdgcn_rcpf(x); }

__device__ __forceinline__ float sigmoid_fast(float x) {
    return frcp(1.f + exp2f(-x * LOG2E));
}
__device__ __forceinline__ float tanh_fast(float x) {
    float e = exp2f(x * (2.f * LOG2E));
    return 1.f - 2.f * frcp(1.f + e);
}
__device__ __forceinline__ float softplus_fast(float x) {
    float t = exp2f(-fabsf(x) * LOG2E);
    return fmaxf(x, 0.f) + LN2 * log2f(1.f + t);
}

// pre_emb[e][t] = sum_k in_emb[e][k] * Wx[k][t] + bias[t]   (103 x 448)
__global__ void pre_emb_kernel(const float* __restrict__ in_emb,
                               const float* __restrict__ Wx,
                               const float* __restrict__ bias,
                               float* __restrict__ pre_emb) {
    int e = blockIdx.x;
    int t = threadIdx.x;
    float acc = bias[t];
#pragma unroll
    for (int k = 0; k < HH; ++k)
        acc = fmaf(in_emb[e * HH + k], Wx[k * GG + t], acc);
    pre_emb[e * GG + t] = acc;
}

// Raw barrier: fence LDS only (lgkmcnt); global loads/stores stay in flight.
__device__ __forceinline__ void step_barrier() {
    __builtin_amdgcn_sched_barrier(0);
    asm volatile("s_waitcnt lgkmcnt(0)" ::: "memory");
    __builtin_amdgcn_s_barrier();
    __builtin_amdgcn_sched_barrier(0);
}

// One block per batch row; 9 waves (7 gate + 2 logit), ONE raw barrier/step.
// K-split-2 GEMV: lane (h2=l>>5, s5=l&31) accumulates columns {s5, 32+s5} of
// its wave's 64-col block over k in [32*h2, 32*h2+32) only => per-wave h read
// is 8 ds_read_b128 (vs 16 full-vector broadcasts in the 1403us R1 version),
// then one __shfl_xor(32) reduce. State update (c/cb/h, fp32) is computed
// REDUNDANTLY by all 7 gate waves (lane=element) from gbuf written last step;
// each wave publishes h into its PRIVATE double-buffered LDS slice and reads
// it back wave-synchronously (no barrier). Logit waves dot h_{t-1} against
// register-resident out_emb columns (same K-split) and store straight to out
// behind the lgkm-only barrier. All math fp32 -> absmax identical.
__launch_bounds__(NTHREADS, 1)
__global__ void scan_kernel(const int* __restrict__ event,
                            const float* __restrict__ dtime,
                            const float* __restrict__ pre_emb,
                            const float* __restrict__ Wh,
                            const float* __restrict__ oe,
                            float* __restrict__ out) {
    const int b   = blockIdx.x;
    const int tid = threadIdx.x;
    const int w   = tid >> 6;     // wave 0..8
    const int l   = tid & 63;     // lane
    const int h2  = l >> 5;       // k-half 0..1
    const int s5  = l & 31;       // column slot 0..31

    __shared__ float gbuf[2][7][HH];     // gate values (double-buffered)
    __shared__ __align__(16) float h_sw[7][2][HH];  // per-gate-wave h slices
    __shared__ int   evoff_s[NSTAGE];    // pre_emb row offsets (float units)
    __shared__ float dtl_s[NSTAGE];

    const bool is_gate = (w < 7);
    const int  jw      = w - 7;          // logit wave index 0..1

    const int*   ev_row  = event + b * T2;
    const float* dt_row  = dtime + b * T2;
    float*       out_row = out + (size_t)b * TT * KK;

    // ---- stage ev (as row offsets) and dt into LDS (one-time) ----
    for (int i = tid; i < NSTAGE; i += NTHREADS) {
        const int idx = (i < T2) ? i : (T2 - 1);
        evoff_s[i] = ev_row[idx] * GG;
        dtl_s[i]   = dt_row[idx];
    }

    // ---- register-resident weight columns (two per lane, K-half each) ----
    float wA[32], wB[32];
    if (is_gate) {
        const int cA = w * 64 + s5;
        const int cB = w * 64 + 32 + s5;
#pragma unroll
        for (int kk = 0; kk < 32; ++kk) {
            const int k = 32 * h2 + kk;
            wA[kk] = Wh[k * GG + cA];
            wB[kk] = Wh[k * GG + cB];
        }
    } else {
        int cA = 64 * jw + s5;       if (cA > KK - 1) cA = KK - 1;
        int cB = 64 * jw + 32 + s5;  if (cB > KK - 1) cB = KK - 1;
#pragma unroll
        for (int j = 0; j < 8; ++j) {
            ((float4*)wA)[j] = ((const float4*)(oe + cA * HH + 32 * h2))[j];
            ((float4*)wB)[j] = ((const float4*)(oe + cB * HH + 32 * h2))[j];
        }
    }

    __syncthreads();   // evoff_s/dtl_s ready

    // ---- prologue: gbuf[0] = act(pre_0) (h_{-1}=0); pre/dt pipelines ----
    const int colOff = w * 64 + 32 * h2 + s5;   // gate waves: written column
    float preE = 0.f, preO = 0.f, dtE = 0.f, dtO = 0.f;
    int   offE = 0, offO = 0;
    if (is_gate) {
        const float p0  = pre_emb[evoff_s[0] + colOff];
        const float dt0 = dtl_s[1];
        float v0;
        if (w == 2)      v0 = tanh_fast(p0);
        else if (w == 6) v0 = exp2f(-dt0 * log2f(1.f + exp2f(p0 * LOG2E)));
        else             v0 = sigmoid_fast(p0);
        gbuf[0][w][32 * h2 + s5] = v0;

        preE = pre_emb[evoff_s[1] + colOff];   // pre_1 (used at t=0)
        preO = pre_emb[evoff_s[2] + colOff];   // pre_2 (used at t=1)
        offE = evoff_s[3];
        offO = evoff_s[4];
        dtE  = dtl_s[2];                       // dt_1 (used at t=0)
        dtO  = dtl_s[3];                       // dt_2 (used at t=1)
    }
    __syncthreads();

    float c = 0.f, cb = 0.f;

    // logit store bookkeeping
    const int  lcolA = 64 * jw + s5;
    const int  lcolB = 64 * jw + 32 + s5;
    float*     outP  = out_row;

// ---- gate-wave step: state (redundant) + K-split gate GEMV ----
#define GATE_STEP(RB, WB, PRE, OFF, DTV, TIDX)                                  \
    {                                                                           \
        const float pre_use = PRE;                                              \
        PRE = pre_emb[OFF + colOff];           /* refill for step TIDX+2 */     \
        OFF = evoff_s[(TIDX) + 5];                                              \
        const float dt_use = DTV;                                               \
        DTV = dtl_s[(TIDX) + 4];                                                \
        /* state update: lane = element, gates from last step's write */        \
        const float g0 = gbuf[RB][0][l];                                        \
        const float g1 = gbuf[RB][1][l];                                        \
        const float g2 = gbuf[RB][2][l];                                        \
        const float g3 = gbuf[RB][3][l];                                        \
        const float g4 = gbuf[RB][4][l];                                        \
        const float g5 = gbuf[RB][5][l];                                        \
        const float g6 = gbuf[RB][6][l];   /* = exp(-delta*dt), prefused */     \
        const float ci  = fmaf(g1, c, g0 * g2);                                 \
        const float cbi = fmaf(g5, cb, g4 * g2);                                \
        const float cn  = fmaf(ci - cbi, g6, cbi);                              \
        const float h   = g3 * tanh_fast(cn);                                   \
        c  = cn;                                                                \
        cb = cbi;                                                               \
        h_sw[w][RB][l] = h;                                                     \
        /* wave-synchronous readback of this wave's K-half slice */             \
        const float4* h4 = (const float4*)&h_sw[w][RB][32 * h2];                \
        float pA = 0.f, pB = 0.f;                                               \
        _Pragma("unroll") for (int j = 0; j < 8; ++j) {                         \
            const float4 hv = h4[j];                                            \
            pA = fmaf(hv.x, wA[4 * j + 0], pA);                                 \
            pB = fmaf(hv.x, wB[4 * j + 0], pB);                                 \
            pA = fmaf(hv.y, wA[4 * j + 1], pA);                                 \
            pB = fmaf(hv.y, wB[4 * j + 1], pB);                                 \
            pA = fmaf(hv.z, wA[4 * j + 2], pA);                                 \
            pB = fmaf(hv.z, wB[4 * j + 2], pB);                                 \
            pA = fmaf(hv.w, wA[4 * j + 3], pA);                                 \
            pB = fmaf(hv.w, wB[4 * j + 3], pB);                                 \
        }                                                                       \
        pA += __shfl_xor(pA, 32);                                               \
        pB += __shfl_xor(pB, 32);                                               \
        const float acc = pre_use + (h2 ? pB : pA);                             \
        float val;                                                              \
        if (w == 2)      val = tanh_fast(acc);                                  \
        else if (w == 6) val = exp2f(-dt_use * log2f(1.f + exp2f(acc * LOG2E)));\
        else             val = sigmoid_fast(acc);                               \
        gbuf[WB][w][32 * h2 + s5] = val;                                        \
    }

// ---- logit-wave step: dot h (in h_sw[0][HB]) vs oe cols, store row ----
#define LOGIT_STEP(HB, DO_STORE)                                                \
    {                                                                           \
        const float4* h4 = (const float4*)&h_sw[0][HB][32 * h2];                \
        float pA = 0.f, pB = 0.f;                                               \
        _Pragma("unroll") for (int j = 0; j < 8; ++j) {                         \
            const float4 hv = h4[j];                                            \
            pA = fmaf(hv.x, wA[4 * j + 0], pA);                                 \
            pB = fmaf(hv.x, wB[4 * j + 0], pB);                                 \
            pA = fmaf(hv.y, wA[4 * j + 1], pA);                                 \
            pB = fmaf(hv.y, wB[4 * j + 1], pB);                                 \
            pA = fmaf(hv.z, wA[4 * j + 2], pA);                                 \
            pB = fmaf(hv.z, wB[4 * j + 2], pB);                                 \
            pA = fmaf(hv.w, wA[4 * j + 3], pA);                                 \
            pB = fmaf(hv.w, wB[4 * j + 3], pB);                                 \
        }                                                                       \
        pA += __shfl_xor(pA, 32);                                               \
        pB += __shfl_xor(pB, 32);                                               \
        if (DO_STORE) {                                                         \
            const float lg  = h2 ? pB : pA;                                     \
            const int   col = h2 ? lcolB : lcolA;                               \
            if (col < KK) outP[col] = softplus_fast(lg);                        \
            outP += KK;                                                         \
        }                                                                       \
    }

    if (is_gate) __builtin_amdgcn_s_setprio(1);

    // main loop: 1024 double-steps cover t = 0..2047
    for (int tp = 0; tp < (TT - 1) / 2; ++tp) {
        const int te = 2 * tp;
        if (is_gate) { GATE_STEP(0, 1, preE, offE, dtE, te) }
        else         { LOGIT_STEP(1, (tp > 0)) }   // h_{t-1} in buf 1 (t even)
        step_barrier();
        if (is_gate) { GATE_STEP(1, 0, preO, offO, dtO, te + 1) }
        else         { LOGIT_STEP(0, true) }       // h_{t-1} in buf 0 (t odd)
        step_barrier();
    }
    // tail step t = 2048 (even: read gbuf[0]/h buf 0, write gbuf[1])
    if (is_gate) { GATE_STEP(0, 1, preE, offE, dtE, TT - 1) }
    else         { LOGIT_STEP(1, true) }
    step_barrier();
    if (is_gate) __builtin_amdgcn_s_setprio(0);

    // final logits: h_{2048} lives in h_sw[0][0] (t=2048 even -> RB=0)
    if (!is_gate) { LOGIT_STEP(0, true) }

#undef GATE_STEP
#undef LOGIT_STEP
}

extern "C" void kernel_launch(void* const* d_in, const int* in_sizes, int n_in,
                              void* d_out, int out_size, void* d_ws, size_t ws_size,
                              hipStream_t stream) {
    const int*   event  = (const int*)d_in[0];
    const float* dtime  = (const float*)d_in[1];
    const float* in_emb = (const float*)d_in[2];
    const float* Wx     = (const float*)d_in[3];
    const float* Wh     = (const float*)d_in[4];
    const float* bias   = (const float*)d_in[5];
    const float* oe     = (const float*)d_in[6];
    float*       out    = (float*)d_out;

    float* pre_emb = (float*)d_ws;  // 103*448*4 = 184,576 bytes

    pre_emb_kernel<<<NE, GG, 0, stream>>>(in_emb, Wx, bias, pre_emb);
    scan_kernel<<<BB, NTHREADS, 0, stream>>>(event, dtime, pre_emb, Wh, oe, out);
}